// Round 8
// baseline (132.923 us; speedup 1.0000x reference)
//
#include <hip/hip_runtime.h>
#include <math.h>

#define D      256
#define NSEC   10
#define EPS    1e-6f
#define SLICE  0.1f

// ws float layout
#define WS_SUMS 0                      // [0,2560) per-sector sums
#define WS_CNT  (NSEC * D)             // [2560,2570) per-sector counts
#define WS_PART (NSEC * D + NSEC)      // [2570,2826) per-block distance partials (256)
#define WS_ZERO_FLOATS (NSEC * D + NSEC)   // only sums+counts need zeroing

#define DIST_BLOCKS 256
#define SWEEPS 3   // INSTRUMENTATION: x3 inner work so k_dist surfaces in top-5 counters

__global__ void k_zero(float* __restrict__ ws) {
    int i = blockIdx.x * blockDim.x + threadIdx.x;
    if (i < WS_ZERO_FLOATS) ws[i] = 0.f;
}

__global__ __launch_bounds__(256) void k_sums(const float* __restrict__ emb,
                                              const int* __restrict__ sec,
                                              float* __restrict__ ws, int nrows) {
    const int lane = threadIdx.x & 63;
    const int wid  = threadIdx.x >> 6;          // 0..3
    const int gw   = blockIdx.x * 4 + wid;      // global wave id
    const int nw   = gridDim.x * 4;

    float4 acc[NSEC];
    float  cnt[NSEC];
#pragma unroll
    for (int s = 0; s < NSEC; ++s) { acc[s] = make_float4(0.f, 0.f, 0.f, 0.f); cnt[s] = 0.f; }

    const float* ep = emb + (size_t)lane * 4;

    auto accum = [&](int sv, float4 v) {
        const int s = __builtin_amdgcn_readfirstlane(sv);  // wave-uniform -> SGPR branch
#pragma unroll
        for (int ss = 0; ss < NSEC; ++ss) {
            if (s == ss) {   // scalar branch; acc index compile-time constant (no scratch)
                acc[ss].x += v.x; acc[ss].y += v.y; acc[ss].z += v.z; acc[ss].w += v.w;
                cnt[ss] += 1.f;
            }
        }
    };

    int r = gw;
    for (; r + 3 * nw < nrows; r += 4 * nw) {
        const int s0 = sec[r];
        const int s1 = sec[r + nw];
        const int s2 = sec[r + 2 * nw];
        const int s3 = sec[r + 3 * nw];
        const float4 v0 = *reinterpret_cast<const float4*>(ep + (size_t)r * D);
        const float4 v1 = *reinterpret_cast<const float4*>(ep + (size_t)(r + nw) * D);
        const float4 v2 = *reinterpret_cast<const float4*>(ep + (size_t)(r + 2 * nw) * D);
        const float4 v3 = *reinterpret_cast<const float4*>(ep + (size_t)(r + 3 * nw) * D);
        accum(s0, v0); accum(s1, v1); accum(s2, v2); accum(s3, v3);
    }
    for (; r < nrows; r += nw)
        accum(sec[r], *reinterpret_cast<const float4*>(ep + (size_t)r * D));

    __shared__ float lsum[NSEC * D];   // 10 KB
    __shared__ float lcnt[NSEC];
    for (int i = threadIdx.x; i < NSEC * D; i += 256) lsum[i] = 0.f;
    if (threadIdx.x < NSEC) lcnt[threadIdx.x] = 0.f;
    __syncthreads();

    for (int w = 0; w < 4; ++w) {
        if (wid == w) {
#pragma unroll
            for (int ss = 0; ss < NSEC; ++ss) {
                float* p = &lsum[ss * D + lane * 4];
                p[0] += acc[ss].x; p[1] += acc[ss].y; p[2] += acc[ss].z; p[3] += acc[ss].w;
                if (lane == 0) lcnt[ss] += cnt[ss];
            }
        }
        __syncthreads();
    }

#pragma unroll
    for (int ss = 0; ss < NSEC; ++ss)
        atomicAdd(&ws[WS_SUMS + ss * D + threadIdx.x], lsum[ss * D + threadIdx.x]);
    if (threadIdx.x < NSEC)
        atomicAdd(&ws[WS_CNT + threadIdx.x], lcnt[threadIdx.x]);
}

// IDENTICAL body to R7, but the row sweep runs SWEEPS times (unroll 1) so the
// dispatch exceeds the harness fills and its counter row becomes visible.
__global__ __launch_bounds__(1024, 4) void k_dist(const float* __restrict__ temb,
                                                  const float* __restrict__ tsl,
                                                  float* __restrict__ ws, int nrows) {
    __shared__ float lc[NSEC * D];
    for (int i = threadIdx.x; i < NSEC * D; i += 1024) {
        const int s = i >> 8;  // i / D
        lc[i] = ws[WS_SUMS + i] / ws[WS_CNT + s];
    }
    __syncthreads();

    const int lane = threadIdx.x & 63;
    const int wid  = threadIdx.x >> 6;            // 0..15
    const int gw   = blockIdx.x * 16 + wid;       // global wave id (4096 total)
    const int nw   = gridDim.x * 16;

    const float* tp = temb + (size_t)lane * 4;

    float wacc = 0.f;
#pragma unroll 1
    for (int sweep = 0; sweep < SWEEPS; ++sweep) {
        int r = gw;
        for (; r + 7 * nw < nrows; r += 8 * nw) {
            float  t[8];
            float4 v[8];
#pragma unroll
            for (int k = 0; k < 8; ++k) t[k] = tsl[r + k * nw];
#pragma unroll
            for (int k = 0; k < 8; ++k)
                v[k] = *reinterpret_cast<const float4*>(tp + (size_t)(r + k * nw) * D);

            float l[8];
#pragma unroll
            for (int k = 0; k < 8; ++k) {
                int s = (int)floorf(t[k] / SLICE);
                s = s < 0 ? 0 : (s > NSEC - 1 ? NSEC - 1 : s);
                const float4 c = *reinterpret_cast<const float4*>(&lc[s * D + lane * 4]);
                const float dx = v[k].x - c.x + EPS;
                const float dy = v[k].y - c.y + EPS;
                const float dz = v[k].z - c.z + EPS;
                const float dw = v[k].w - c.w + EPS;
                l[k] = dx * dx + dy * dy + dz * dz + dw * dw;
            }

#pragma unroll
            for (int off = 32; off >= 1; off >>= 1) {
#pragma unroll
                for (int k = 0; k < 8; ++k) l[k] += __shfl_xor(l[k], off, 64);
            }
#pragma unroll
            for (int k = 0; k < 8; ++k) wacc += sqrtf(l[k]);
        }
        for (; r < nrows; r += nw) {
            const float si = tsl[r];
            int s = (int)floorf(si / SLICE);
            s = s < 0 ? 0 : (s > NSEC - 1 ? NSEC - 1 : s);
            const float4 vv = *reinterpret_cast<const float4*>(tp + (size_t)r * D);
            const float4 c = *reinterpret_cast<const float4*>(&lc[s * D + lane * 4]);
            const float dx = vv.x - c.x + EPS;
            const float dy = vv.y - c.y + EPS;
            const float dz = vv.z - c.z + EPS;
            const float dw = vv.w - c.w + EPS;
            float loc = dx * dx + dy * dy + dz * dz + dw * dw;
#pragma unroll
            for (int off = 32; off >= 1; off >>= 1) loc += __shfl_xor(loc, off, 64);
            wacc += sqrtf(loc);
        }
    }

    __shared__ float wsum[16];
    if (lane == 0) wsum[wid] = wacc;
    __syncthreads();
    if (threadIdx.x == 0) {
        float t = 0.f;
#pragma unroll
        for (int k = 0; k < 16; ++k) t += wsum[k];
        ws[WS_PART + blockIdx.x] = t;   // plain store, private slot (sum of SWEEPS copies)
    }
}

// single block reduces the 256 partials; invN folds in the 1/SWEEPS factor
__global__ __launch_bounds__(256) void k_final(const float* __restrict__ ws,
                                               float* __restrict__ out, float invN) {
    float v = ws[WS_PART + threadIdx.x];
#pragma unroll
    for (int off = 32; off >= 1; off >>= 1) v += __shfl_xor(v, off, 64);
    __shared__ float s4[4];
    if ((threadIdx.x & 63) == 0) s4[threadIdx.x >> 6] = v;
    __syncthreads();
    if (threadIdx.x == 0) out[0] = (s4[0] + s4[1] + s4[2] + s4[3]) * invN;
}

extern "C" void kernel_launch(void* const* d_in, const int* in_sizes, int n_in,
                              void* d_out, int out_size, void* d_ws, size_t ws_size,
                              hipStream_t stream) {
    const float* semb = (const float*)d_in[0];   // [nS, 256] f32
    const int*   ssec = (const int*)d_in[1];     // [nS] i32
    const float* temb = (const float*)d_in[2];   // [nT, 256] f32
    const float* tsl  = (const float*)d_in[3];   // [nT] f32
    float* ws  = (float*)d_ws;
    float* out = (float*)d_out;
    const int nS = in_sizes[1];
    const int nT = in_sizes[3];

    hipLaunchKernelGGL(k_zero, dim3((WS_ZERO_FLOATS + 255) / 256), dim3(256), 0, stream, ws);
    hipLaunchKernelGGL(k_sums, dim3(1024), dim3(256), 0, stream, semb, ssec, ws, nS);
    hipLaunchKernelGGL(k_dist, dim3(DIST_BLOCKS), dim3(1024), 0, stream, temb, tsl, ws, nT);
    hipLaunchKernelGGL(k_final, dim3(1), dim3(256), 0, stream, ws, out,
                       1.0f / ((float)nT * (float)SWEEPS));
}

// Round 9
// 113.500 us; speedup vs baseline: 1.1711x; 1.1711x over previous
//
#include <hip/hip_runtime.h>
#include <math.h>

#define D      256
#define NSEC   10
#define EPS    1e-6f
#define SLICE  0.1f

#define NSUM_BLOCKS  1024
#define NDIST_BLOCKS 1024
#define SLAB_STRIDE  (NSEC * D + NSEC)          // 2570 floats per block slab

// atomic-free ws layout (floats)
#define WS_SLAB 0                                // [0, 1024*2570)
#define WS_CENT ((size_t)NSUM_BLOCKS * SLAB_STRIDE)          // +2560
#define WS_PART (WS_CENT + NSEC * D)                         // +1024
#define WS_NEED ((WS_PART + NDIST_BLOCKS) * sizeof(float))

// ---------------- primary (atomic-free) path ----------------

__global__ __launch_bounds__(256) void k_sums_slab(const float* __restrict__ emb,
                                                   const int* __restrict__ sec,
                                                   float* __restrict__ ws, int nrows) {
    const int lane = threadIdx.x & 63;
    const int wid  = threadIdx.x >> 6;
    const int gw   = blockIdx.x * 4 + wid;
    const int nw   = gridDim.x * 4;

    float4 acc[NSEC];
    float  cnt[NSEC];
#pragma unroll
    for (int s = 0; s < NSEC; ++s) { acc[s] = make_float4(0.f, 0.f, 0.f, 0.f); cnt[s] = 0.f; }

    const float* ep = emb + (size_t)lane * 4;

    auto accum = [&](int sv, float4 v) {
        const int s = __builtin_amdgcn_readfirstlane(sv);
#pragma unroll
        for (int ss = 0; ss < NSEC; ++ss) {
            if (s == ss) {
                acc[ss].x += v.x; acc[ss].y += v.y; acc[ss].z += v.z; acc[ss].w += v.w;
                cnt[ss] += 1.f;
            }
        }
    };

    int r = gw;
    for (; r + 3 * nw < nrows; r += 4 * nw) {
        const int s0 = sec[r];
        const int s1 = sec[r + nw];
        const int s2 = sec[r + 2 * nw];
        const int s3 = sec[r + 3 * nw];
        const float4 v0 = *reinterpret_cast<const float4*>(ep + (size_t)r * D);
        const float4 v1 = *reinterpret_cast<const float4*>(ep + (size_t)(r + nw) * D);
        const float4 v2 = *reinterpret_cast<const float4*>(ep + (size_t)(r + 2 * nw) * D);
        const float4 v3 = *reinterpret_cast<const float4*>(ep + (size_t)(r + 3 * nw) * D);
        accum(s0, v0); accum(s1, v1); accum(s2, v2); accum(s3, v3);
    }
    for (; r < nrows; r += nw)
        accum(sec[r], *reinterpret_cast<const float4*>(ep + (size_t)r * D));

    __shared__ float lsum[NSEC * D];
    __shared__ float lcnt[NSEC];
    for (int i = threadIdx.x; i < NSEC * D; i += 256) lsum[i] = 0.f;
    if (threadIdx.x < NSEC) lcnt[threadIdx.x] = 0.f;
    __syncthreads();

    for (int w = 0; w < 4; ++w) {
        if (wid == w) {
#pragma unroll
            for (int ss = 0; ss < NSEC; ++ss) {
                float* p = &lsum[ss * D + lane * 4];
                p[0] += acc[ss].x; p[1] += acc[ss].y; p[2] += acc[ss].z; p[3] += acc[ss].w;
                if (lane == 0) lcnt[ss] += cnt[ss];
            }
        }
        __syncthreads();
    }

    // PLAIN coalesced stores to this block's private slab — zero atomics
    float* slab = ws + (size_t)blockIdx.x * SLAB_STRIDE;
    for (int i = threadIdx.x; i < NSEC * D; i += 256) slab[i] = lsum[i];
    if (threadIdx.x < NSEC) slab[NSEC * D + threadIdx.x] = lcnt[threadIdx.x];
}

// one block per sector: reduce 1024 slabs -> center vector
__global__ __launch_bounds__(1024) void k_centers(float* __restrict__ ws) {
    const int s = blockIdx.x;
    const int t = threadIdx.x;
    const int d  = t & 255;
    const int ch = t >> 8;            // 0..3 slab chunks of 256

    __shared__ float red[1024];
    __shared__ float part[4][256];

    red[t] = ws[(size_t)t * SLAB_STRIDE + NSEC * D + s];
    __syncthreads();
    for (int off = 512; off >= 1; off >>= 1) {
        if (t < off) red[t] += red[t + off];
        __syncthreads();
    }

    float a0 = 0.f, a1 = 0.f, a2 = 0.f, a3 = 0.f;
    const size_t base = (size_t)s * D + d;
    for (int b = ch * 256; b < ch * 256 + 256; b += 4) {
        a0 += ws[(size_t)b       * SLAB_STRIDE + base];
        a1 += ws[(size_t)(b + 1) * SLAB_STRIDE + base];
        a2 += ws[(size_t)(b + 2) * SLAB_STRIDE + base];
        a3 += ws[(size_t)(b + 3) * SLAB_STRIDE + base];
    }
    part[ch][d] = a0 + a1 + a2 + a3;
    __syncthreads();
    if (t < 256)
        ws[WS_CENT + (size_t)s * D + t] =
            (part[0][t] + part[1][t] + part[2][t] + part[3][t]) / red[0];
}

// 1024 blocks x 256 threads (4 blocks/CU slack). No prologue, no LDS staging:
// centers read directly from global (10 KB, L1/L2-cached). Plain-store partial.
__global__ __launch_bounds__(256) void k_dist_direct(const float* __restrict__ temb,
                                                     const float* __restrict__ tsl,
                                                     const float* __restrict__ cent,
                                                     float* __restrict__ part, int nrows) {
    const int lane = threadIdx.x & 63;
    const int wid  = threadIdx.x >> 6;
    const int gw   = blockIdx.x * 4 + wid;
    const int nw   = gridDim.x * 4;

    const float* tp = temb + (size_t)lane * 4;
    const float* cp = cent + (size_t)lane * 4;

    auto rowdist = [&](float si, float4 v) -> float {
        int s = (int)floorf(si / SLICE);
        s = s < 0 ? 0 : (s > NSEC - 1 ? NSEC - 1 : s);
        const float4 c = *reinterpret_cast<const float4*>(cp + (size_t)s * D);
        const float dx = v.x - c.x + EPS;
        const float dy = v.y - c.y + EPS;
        const float dz = v.z - c.z + EPS;
        const float dw = v.w - c.w + EPS;
        float loc = dx * dx + dy * dy + dz * dz + dw * dw;
#pragma unroll
        for (int off = 32; off >= 1; off >>= 1) loc += __shfl_xor(loc, off, 64);
        return loc;
    };

    float wacc = 0.f;
    int r = gw;
    for (; r + 3 * nw < nrows; r += 4 * nw) {
        const float t0 = tsl[r];
        const float t1 = tsl[r + nw];
        const float t2 = tsl[r + 2 * nw];
        const float t3 = tsl[r + 3 * nw];
        const float4 v0 = *reinterpret_cast<const float4*>(tp + (size_t)r * D);
        const float4 v1 = *reinterpret_cast<const float4*>(tp + (size_t)(r + nw) * D);
        const float4 v2 = *reinterpret_cast<const float4*>(tp + (size_t)(r + 2 * nw) * D);
        const float4 v3 = *reinterpret_cast<const float4*>(tp + (size_t)(r + 3 * nw) * D);
        float l0 = rowdist(t0, v0);
        float l1 = rowdist(t1, v1);
        float l2 = rowdist(t2, v2);
        float l3 = rowdist(t3, v3);
        if (lane == 0) wacc += sqrtf(l0) + sqrtf(l1) + sqrtf(l2) + sqrtf(l3);
    }
    for (; r < nrows; r += nw) {
        float l = rowdist(tsl[r], *reinterpret_cast<const float4*>(tp + (size_t)r * D));
        if (lane == 0) wacc += sqrtf(l);
    }

    __shared__ float wsum[4];
    if (lane == 0) wsum[wid] = wacc;
    __syncthreads();
    if (threadIdx.x == 0)
        part[blockIdx.x] = wsum[0] + wsum[1] + wsum[2] + wsum[3];
}

__global__ __launch_bounds__(1024) void k_final2(const float* __restrict__ part,
                                                 float* __restrict__ out, float invN) {
    float v = part[threadIdx.x];
#pragma unroll
    for (int off = 32; off >= 1; off >>= 1) v += __shfl_xor(v, off, 64);
    __shared__ float s16[16];
    if ((threadIdx.x & 63) == 0) s16[threadIdx.x >> 6] = v;
    __syncthreads();
    if (threadIdx.x == 0) {
        float tot = 0.f;
#pragma unroll
        for (int k = 0; k < 16; ++k) tot += s16[k];
        out[0] = tot * invN;
    }
}

// ---------------- fallback path (ws too small): R7 structure ----------------

#define FB_SUMS 0
#define FB_CNT  (NSEC * D)
#define FB_PART (NSEC * D + NSEC)
#define FB_ZERO (NSEC * D + NSEC)

__global__ void fb_zero(float* __restrict__ ws) {
    int i = blockIdx.x * blockDim.x + threadIdx.x;
    if (i < FB_ZERO) ws[i] = 0.f;
}

__global__ __launch_bounds__(256) void fb_sums(const float* __restrict__ emb,
                                               const int* __restrict__ sec,
                                               float* __restrict__ ws, int nrows) {
    const int lane = threadIdx.x & 63;
    const int wid  = threadIdx.x >> 6;
    const int gw   = blockIdx.x * 4 + wid;
    const int nw   = gridDim.x * 4;
    float4 acc[NSEC]; float cnt[NSEC];
#pragma unroll
    for (int s = 0; s < NSEC; ++s) { acc[s] = make_float4(0.f,0.f,0.f,0.f); cnt[s] = 0.f; }
    const float* ep = emb + (size_t)lane * 4;
    auto accum = [&](int sv, float4 v) {
        const int s = __builtin_amdgcn_readfirstlane(sv);
#pragma unroll
        for (int ss = 0; ss < NSEC; ++ss)
            if (s == ss) { acc[ss].x+=v.x; acc[ss].y+=v.y; acc[ss].z+=v.z; acc[ss].w+=v.w; cnt[ss]+=1.f; }
    };
    for (int r = gw; r < nrows; r += nw)
        accum(sec[r], *reinterpret_cast<const float4*>(ep + (size_t)r * D));
    __shared__ float lsum[NSEC * D]; __shared__ float lcnt[NSEC];
    for (int i = threadIdx.x; i < NSEC * D; i += 256) lsum[i] = 0.f;
    if (threadIdx.x < NSEC) lcnt[threadIdx.x] = 0.f;
    __syncthreads();
    for (int w = 0; w < 4; ++w) {
        if (wid == w) {
#pragma unroll
            for (int ss = 0; ss < NSEC; ++ss) {
                float* p = &lsum[ss * D + lane * 4];
                p[0]+=acc[ss].x; p[1]+=acc[ss].y; p[2]+=acc[ss].z; p[3]+=acc[ss].w;
                if (lane == 0) lcnt[ss] += cnt[ss];
            }
        }
        __syncthreads();
    }
#pragma unroll
    for (int ss = 0; ss < NSEC; ++ss)
        atomicAdd(&ws[FB_SUMS + ss * D + threadIdx.x], lsum[ss * D + threadIdx.x]);
    if (threadIdx.x < NSEC) atomicAdd(&ws[FB_CNT + threadIdx.x], lcnt[threadIdx.x]);
}

__global__ __launch_bounds__(256) void fb_dist(const float* __restrict__ temb,
                                               const float* __restrict__ tsl,
                                               float* __restrict__ ws, int nrows) {
    __shared__ float lc[NSEC * D];
    for (int i = threadIdx.x; i < NSEC * D; i += 256)
        lc[i] = ws[FB_SUMS + i] / ws[FB_CNT + (i >> 8)];
    __syncthreads();
    const int lane = threadIdx.x & 63;
    const int wid  = threadIdx.x >> 6;
    const int gw   = blockIdx.x * 4 + wid;
    const int nw   = gridDim.x * 4;
    const float* tp = temb + (size_t)lane * 4;
    float wacc = 0.f;
    for (int r = gw; r < nrows; r += nw) {
        const float si = tsl[r];
        int s = (int)floorf(si / SLICE);
        s = s < 0 ? 0 : (s > NSEC - 1 ? NSEC - 1 : s);
        const float4 v = *reinterpret_cast<const float4*>(tp + (size_t)r * D);
        const float4 c = *reinterpret_cast<const float4*>(&lc[s * D + lane * 4]);
        const float dx = v.x-c.x+EPS, dy = v.y-c.y+EPS, dz = v.z-c.z+EPS, dw = v.w-c.w+EPS;
        float loc = dx*dx + dy*dy + dz*dz + dw*dw;
#pragma unroll
        for (int off = 32; off >= 1; off >>= 1) loc += __shfl_xor(loc, off, 64);
        if (lane == 0) wacc += sqrtf(loc);
    }
    __shared__ float wsum[4];
    if (lane == 0) wsum[wid] = wacc;
    __syncthreads();
    if (threadIdx.x == 0) ws[FB_PART + blockIdx.x] = wsum[0]+wsum[1]+wsum[2]+wsum[3];
}

__global__ __launch_bounds__(1024) void fb_final(const float* __restrict__ ws,
                                                 float* __restrict__ out, float invN) {
    float v = ws[FB_PART + threadIdx.x];
#pragma unroll
    for (int off = 32; off >= 1; off >>= 1) v += __shfl_xor(v, off, 64);
    __shared__ float s16[16];
    if ((threadIdx.x & 63) == 0) s16[threadIdx.x >> 6] = v;
    __syncthreads();
    if (threadIdx.x == 0) {
        float tot = 0.f;
#pragma unroll
        for (int k = 0; k < 16; ++k) tot += s16[k];
        out[0] = tot * invN;
    }
}

extern "C" void kernel_launch(void* const* d_in, const int* in_sizes, int n_in,
                              void* d_out, int out_size, void* d_ws, size_t ws_size,
                              hipStream_t stream) {
    const float* semb = (const float*)d_in[0];
    const int*   ssec = (const int*)d_in[1];
    const float* temb = (const float*)d_in[2];
    const float* tsl  = (const float*)d_in[3];
    float* ws  = (float*)d_ws;
    float* out = (float*)d_out;
    const int nS = in_sizes[1];
    const int nT = in_sizes[3];
    const float invN = 1.0f / (float)nT;

    if (ws_size >= WS_NEED) {
        hipLaunchKernelGGL(k_sums_slab, dim3(NSUM_BLOCKS), dim3(256), 0, stream,
                           semb, ssec, ws, nS);
        hipLaunchKernelGGL(k_centers, dim3(NSEC), dim3(1024), 0, stream, ws);
        hipLaunchKernelGGL(k_dist_direct, dim3(NDIST_BLOCKS), dim3(256), 0, stream,
                           temb, tsl, ws + WS_CENT, ws + WS_PART, nT);
        hipLaunchKernelGGL(k_final2, dim3(1), dim3(1024), 0, stream,
                           ws + WS_PART, out, invN);
    } else {
        hipLaunchKernelGGL(fb_zero, dim3((FB_ZERO + 255) / 256), dim3(256), 0, stream, ws);
        hipLaunchKernelGGL(fb_sums, dim3(1024), dim3(256), 0, stream, semb, ssec, ws, nS);
        hipLaunchKernelGGL(fb_dist, dim3(1024), dim3(256), 0, stream, temb, tsl, ws, nT);
        hipLaunchKernelGGL(fb_final, dim3(1), dim3(1024), 0, stream, ws, out, invN);
    }
}

// Round 10
// 106.565 us; speedup vs baseline: 1.2473x; 1.0651x over previous
//
#include <hip/hip_runtime.h>
#include <math.h>

#define D      256
#define NSEC   10
#define EPS    1e-6f
#define SLICE  0.1f

// ws float layout
#define WS_SUMS 0                       // [0,2560)   per-sector sums
#define WS_CNT  (NSEC * D)              // [2560,2570) per-sector counts
#define WS_CENT (NSEC * D + NSEC)       // [2570,5130) centers
#define WS_K    (WS_CENT + NSEC * D)    // [5130,5140) per-sector constant K
#define WS_PART (WS_K + NSEC)           // [5140,...)  per-block distance partials
#define WS_ZERO_FLOATS (NSEC * D + NSEC)

__global__ void k_zero(float* __restrict__ ws) {
    int i = blockIdx.x * blockDim.x + threadIdx.x;
    if (i < WS_ZERO_FLOATS) ws[i] = 0.f;
}

// ---- k_sums: unchanged R7 structure (measured ~5.3 TB/s) ----
__global__ __launch_bounds__(256) void k_sums(const float* __restrict__ emb,
                                              const int* __restrict__ sec,
                                              float* __restrict__ ws, int nrows) {
    const int lane = threadIdx.x & 63;
    const int wid  = threadIdx.x >> 6;
    const int gw   = blockIdx.x * 4 + wid;
    const int nw   = gridDim.x * 4;

    float4 acc[NSEC];
    float  cnt[NSEC];
#pragma unroll
    for (int s = 0; s < NSEC; ++s) { acc[s] = make_float4(0.f, 0.f, 0.f, 0.f); cnt[s] = 0.f; }

    const float* ep = emb + (size_t)lane * 4;

    auto accum = [&](int sv, float4 v) {
        const int s = __builtin_amdgcn_readfirstlane(sv);
#pragma unroll
        for (int ss = 0; ss < NSEC; ++ss) {
            if (s == ss) {
                acc[ss].x += v.x; acc[ss].y += v.y; acc[ss].z += v.z; acc[ss].w += v.w;
                cnt[ss] += 1.f;
            }
        }
    };

    int r = gw;
    for (; r + 3 * nw < nrows; r += 4 * nw) {
        const int s0 = sec[r];
        const int s1 = sec[r + nw];
        const int s2 = sec[r + 2 * nw];
        const int s3 = sec[r + 3 * nw];
        const float4 v0 = *reinterpret_cast<const float4*>(ep + (size_t)r * D);
        const float4 v1 = *reinterpret_cast<const float4*>(ep + (size_t)(r + nw) * D);
        const float4 v2 = *reinterpret_cast<const float4*>(ep + (size_t)(r + 2 * nw) * D);
        const float4 v3 = *reinterpret_cast<const float4*>(ep + (size_t)(r + 3 * nw) * D);
        accum(s0, v0); accum(s1, v1); accum(s2, v2); accum(s3, v3);
    }
    for (; r < nrows; r += nw)
        accum(sec[r], *reinterpret_cast<const float4*>(ep + (size_t)r * D));

    __shared__ float lsum[NSEC * D];
    __shared__ float lcnt[NSEC];
    for (int i = threadIdx.x; i < NSEC * D; i += 256) lsum[i] = 0.f;
    if (threadIdx.x < NSEC) lcnt[threadIdx.x] = 0.f;
    __syncthreads();

    for (int w = 0; w < 4; ++w) {
        if (wid == w) {
#pragma unroll
            for (int ss = 0; ss < NSEC; ++ss) {
                float* p = &lsum[ss * D + lane * 4];
                p[0] += acc[ss].x; p[1] += acc[ss].y; p[2] += acc[ss].z; p[3] += acc[ss].w;
                if (lane == 0) lcnt[ss] += cnt[ss];
            }
        }
        __syncthreads();
    }

#pragma unroll
    for (int ss = 0; ss < NSEC; ++ss)
        atomicAdd(&ws[WS_SUMS + ss * D + threadIdx.x], lsum[ss * D + threadIdx.x]);
    if (threadIdx.x < NSEC)
        atomicAdd(&ws[WS_CNT + threadIdx.x], lcnt[threadIdx.x]);
}

// ---- centers + per-sector constant K[s] = ||c||^2 - 2*eps*sum(c) + D*eps^2 ----
__global__ __launch_bounds__(256) void k_centers10(float* __restrict__ ws) {
    const int t = threadIdx.x;
    __shared__ float inv[NSEC];
    if (t < NSEC) inv[t] = 1.f / ws[WS_CNT + t];
    __syncthreads();
#pragma unroll
    for (int s = 0; s < NSEC; ++s)
        ws[WS_CENT + s * D + t] = ws[WS_SUMS + s * D + t] * inv[s];
    if (t < NSEC) {
        const float iv = inv[t];
        float cs = 0.f, cn = 0.f;
#pragma unroll 4
        for (int d = 0; d < D; ++d) {
            const float c = ws[WS_SUMS + t * D + d] * iv;
            cs += c; cn += c * c;
        }
        ws[WS_K + t] = cn - 2.f * EPS * cs + (float)D * EPS * EPS;
    }
}

// ---- k_dist_t: thread-per-row, LDS-transposed tiles, no cross-lane in hot loop ----
// dist^2 = sum(t^2) + 2*eps*sum(t) - 2*dot(t,c_s) + K[s]
__global__ __launch_bounds__(256) void k_dist_t(const float* __restrict__ temb,
                                                const float* __restrict__ tsl,
                                                const float* __restrict__ ws,
                                                float* __restrict__ part, int nrows) {
    __shared__ float tile[256 * 33];       // 256 rows x 32 dims, stride 33 (conflict-free)
    __shared__ float c_lds[NSEC * 257];    // centers, stride 257
    __shared__ float K_lds[NSEC];
    const int t = threadIdx.x;

    for (int i = t; i < NSEC * D; i += 256)
        c_lds[(i >> 8) * 257 + (i & 255)] = ws[WS_CENT + i];
    if (t < NSEC) K_lds[t] = ws[WS_K + t];

    const int base = blockIdx.x * 256;
    const int grow = base + t;
    const int crow = grow < nrows ? grow : nrows - 1;
    const float si = tsl[crow];
    int s = (int)floorf(si / SLICE);       // exact reference semantics: divide, floor, clip
    s = s < 0 ? 0 : (s > NSEC - 1 ? NSEC - 1 : s);

    const int lrow   = t >> 3;             // 0..31
    const int lchunk = t & 7;              // 0..7

    // prefetch tile 0 into registers
    float4 v[8];
#pragma unroll
    for (int k = 0; k < 8; ++k) {
        int rr = base + lrow + 32 * k;
        rr = rr < nrows ? rr : nrows - 1;
        v[k] = *reinterpret_cast<const float4*>(temb + (size_t)rr * D + lchunk * 4);
    }

    float sq = 0.f, sm = 0.f, dot = 0.f;
#pragma unroll 1
    for (int dt = 0; dt < 8; ++dt) {
        __syncthreads();   // previous compute done; safe to overwrite tile
#pragma unroll
        for (int k = 0; k < 8; ++k) {
            const int wr = (lrow + 32 * k) * 33 + lchunk * 4;
            tile[wr + 0] = v[k].x; tile[wr + 1] = v[k].y;
            tile[wr + 2] = v[k].z; tile[wr + 3] = v[k].w;
        }
        if (dt < 7) {      // issue next tile's loads; latency hides under compute
#pragma unroll
            for (int k = 0; k < 8; ++k) {
                int rr = base + lrow + 32 * k;
                rr = rr < nrows ? rr : nrows - 1;
                v[k] = *reinterpret_cast<const float4*>(
                    temb + (size_t)rr * D + (dt + 1) * 32 + lchunk * 4);
            }
        }
        __syncthreads();   // tile ready
        const float* trow = &tile[t * 33];
        const float* crp  = &c_lds[s * 257 + dt * 32];
#pragma unroll
        for (int d = 0; d < 32; ++d) {
            const float x  = trow[d];
            const float cv = crp[d];
            sq  = fmaf(x, x, sq);
            sm += x;
            dot = fmaf(x, cv, dot);
        }
    }

    float dist = 0.f;
    if (grow < nrows)
        dist = sqrtf(sq + 2.f * EPS * sm - 2.f * dot + K_lds[s]);

    // single end-of-kernel reduction
#pragma unroll
    for (int off = 32; off >= 1; off >>= 1) dist += __shfl_xor(dist, off, 64);
    __shared__ float ws4[4];
    if ((t & 63) == 0) ws4[t >> 6] = dist;
    __syncthreads();
    if (t == 0) part[blockIdx.x] = ws4[0] + ws4[1] + ws4[2] + ws4[3];
}

__global__ __launch_bounds__(512) void k_final(const float* __restrict__ part,
                                               float* __restrict__ out,
                                               int nparts, float invN) {
    float v = 0.f;
    for (int i = threadIdx.x; i < nparts; i += 512) v += part[i];
#pragma unroll
    for (int off = 32; off >= 1; off >>= 1) v += __shfl_xor(v, off, 64);
    __shared__ float s8[8];
    if ((threadIdx.x & 63) == 0) s8[threadIdx.x >> 6] = v;
    __syncthreads();
    if (threadIdx.x == 0) {
        float tot = 0.f;
#pragma unroll
        for (int k = 0; k < 8; ++k) tot += s8[k];
        out[0] = tot * invN;
    }
}

extern "C" void kernel_launch(void* const* d_in, const int* in_sizes, int n_in,
                              void* d_out, int out_size, void* d_ws, size_t ws_size,
                              hipStream_t stream) {
    const float* semb = (const float*)d_in[0];   // [nS, 256] f32
    const int*   ssec = (const int*)d_in[1];     // [nS] i32
    const float* temb = (const float*)d_in[2];   // [nT, 256] f32
    const float* tsl  = (const float*)d_in[3];   // [nT] f32
    float* ws  = (float*)d_ws;
    float* out = (float*)d_out;
    const int nS = in_sizes[1];
    const int nT = in_sizes[3];
    const int nb = (nT + 255) / 256;             // 391 for nT=100000

    hipLaunchKernelGGL(k_zero, dim3((WS_ZERO_FLOATS + 255) / 256), dim3(256), 0, stream, ws);
    hipLaunchKernelGGL(k_sums, dim3(1024), dim3(256), 0, stream, semb, ssec, ws, nS);
    hipLaunchKernelGGL(k_centers10, dim3(1), dim3(256), 0, stream, ws);
    hipLaunchKernelGGL(k_dist_t, dim3(nb), dim3(256), 0, stream,
                       temb, tsl, ws, ws + WS_PART, nT);
    hipLaunchKernelGGL(k_final, dim3(1), dim3(512), 0, stream,
                       ws + WS_PART, out, nb, 1.0f / (float)nT);
}